// Round 1
// baseline (331.193 us; speedup 1.0000x reference)
//
#include <hip/hip_runtime.h>
#include <hip/hip_bf16.h>

// Attention head: context/softmax over (B=32, S=2048, DEC=512, ENC2=1024)
// d_in[0] = s        (1,32,512)   f32
// d_in[1] = enc      (32,2048,1024) f32
// d_in[2] = W_attn   (512,1536)   f32   [:, :512]=W_s  [:,512:]=W_e
// d_in[3] = W_v      (1,512)      f32
// d_out   = context (32,1024) f32  ++  soft (32,2048) f32

typedef __attribute__((ext_vector_type(8))) short bf16x8;
typedef __attribute__((ext_vector_type(4))) float f32x4;

static __device__ __forceinline__ unsigned short f2bf(float f) {
    union { float f; unsigned u; } v; v.f = f;
    unsigned r = (v.u + 0x7fffu + ((v.u >> 16) & 1u)) >> 16;  // RNE
    return (unsigned short)r;
}

static __device__ __forceinline__ float fast_tanh(float x) {
    // 1 - 2/(e^{2x}+1); saturates correctly at +/-1 for |x| large
    return 1.0f - 2.0f / (__expf(2.0f * x) + 1.0f);
}

// ---------------- prep: sW[b,h] = sum_d s[b,d] * W_attn[h, d] ----------------
__global__ __launch_bounds__(256) void prep_sw(const float* __restrict__ s,
                                               const float* __restrict__ Wat,
                                               float* __restrict__ sW) {
    int id = blockIdx.x * 256 + threadIdx.x;   // 16384 = 32b * 512h
    int b = id >> 9, h = id & 511;
    const float4* wr = (const float4*)(Wat + (size_t)h * 1536);
    const float4* sr = (const float4*)(s + (size_t)b * 512);
    float acc = 0.f;
#pragma unroll 8
    for (int i = 0; i < 128; ++i) {
        float4 w = wr[i], sv = sr[i];
        acc += w.x * sv.x + w.y * sv.y + w.z * sv.z + w.w * sv.w;
    }
    sW[id] = acc;
}

// ---------------- prep: Webf[h][e] = bf16(W_attn[h, 512+e]) ----------------
__global__ __launch_bounds__(256) void prep_we(const float* __restrict__ Wat,
                                               unsigned short* __restrict__ Webf) {
    int id = blockIdx.x * 256 + threadIdx.x;   // 131072 threads, 4 elems each
    int flat = id * 4;
    int h = flat >> 10, e = flat & 1023;
    float4 w = *(const float4*)(Wat + (size_t)h * 1536 + 512 + e);
    union { unsigned short us[4]; uint2 v; } p;
    p.us[0] = f2bf(w.x); p.us[1] = f2bf(w.y); p.us[2] = f2bf(w.z); p.us[3] = f2bf(w.w);
    *(uint2*)(Webf + flat) = p.v;
}

// ---------------- energy+atten: atten[m] = sum_h tanh(sW+enc.W_e^T)*Wv[h] ----
// Block: 64 rows (M) x 512 cols (N), 4 waves each own 128 cols.
// K-loop 1024 in steps of 32 via mfma_f32_16x16x32_bf16.
__global__ __launch_bounds__(256) void energy_kernel(
    const float* __restrict__ enc, const unsigned short* __restrict__ Webf,
    const float* __restrict__ sW, const float* __restrict__ Wv,
    float* __restrict__ atten) {
    __shared__ __align__(16) unsigned short lA[4 * 64 * 8];  // A frags, 4 KiB
    __shared__ float lred[4][64];

    const int t = threadIdx.x;
    const int lane = t & 63;
    const int wave = t >> 6;
    const int m0 = blockIdx.x * 64;
    const int b = m0 >> 11;          // 2048 rows per batch; 64 | 2048
    const int l15 = lane & 15;
    const int lkg = lane >> 4;       // k-group 0..3
    const int n0 = wave * 128;

    float sWv[8], wvv[8];
#pragma unroll
    for (int nf = 0; nf < 8; ++nf) {
        int col = n0 + nf * 16 + l15;
        sWv[nf] = sW[(b << 9) + col];
        wvv[nf] = Wv[col];
    }

    f32x4 acc[4][8];
#pragma unroll
    for (int mf = 0; mf < 4; ++mf)
#pragma unroll
        for (int nf = 0; nf < 8; ++nf) acc[mf][nf] = (f32x4){0.f, 0.f, 0.f, 0.f};

    // staging role: thread t stages exactly the 8 bf16 that (mf=t>>6, lane=t&63)
    // will read -> fragment-ordered LDS, conflict-free ds_read_b128.
    const int sl = t & 63;
    const int srow = (t >> 6) * 16 + (sl & 15);
    const int skg = sl >> 4;
    const float* gA = enc + (size_t)(m0 + srow) * 1024 + skg * 8;
    unsigned short* lst = &lA[t * 8];

    for (int k0 = 0; k0 < 1024; k0 += 32) {
        float4 f0 = *(const float4*)(gA + k0);
        float4 f1 = *(const float4*)(gA + k0 + 4);
        union { unsigned short us[8]; int4 v; } pk;
        pk.us[0] = f2bf(f0.x); pk.us[1] = f2bf(f0.y);
        pk.us[2] = f2bf(f0.z); pk.us[3] = f2bf(f0.w);
        pk.us[4] = f2bf(f1.x); pk.us[5] = f2bf(f1.y);
        pk.us[6] = f2bf(f1.z); pk.us[7] = f2bf(f1.w);
        __syncthreads();                       // prev-iter frag reads done
        *(int4*)lst = pk.v;
        __syncthreads();                       // staging visible

        bf16x8 afr[4];
#pragma unroll
        for (int mf = 0; mf < 4; ++mf)
            afr[mf] = *(const bf16x8*)&lA[(mf * 64 + lane) * 8];

        const unsigned short* gBbase = Webf + k0 + lkg * 8;
#pragma unroll
        for (int nf = 0; nf < 8; ++nf) {
            int col = n0 + nf * 16 + l15;
            bf16x8 bfr = *(const bf16x8*)(gBbase + (size_t)col * 1024);
#pragma unroll
            for (int mf = 0; mf < 4; ++mf)
                acc[mf][nf] = __builtin_amdgcn_mfma_f32_16x16x32_bf16(
                    afr[mf], bfr, acc[mf][nf], 0, 0, 0);
        }
    }

    // epilogue: tanh + dot with Wv over this wave's 128 cols
    float pa[4][4];
#pragma unroll
    for (int mf = 0; mf < 4; ++mf) {
#pragma unroll
        for (int r = 0; r < 4; ++r) pa[mf][r] = 0.f;
#pragma unroll
        for (int nf = 0; nf < 8; ++nf)
#pragma unroll
            for (int r = 0; r < 4; ++r)
                pa[mf][r] += fast_tanh(acc[mf][nf][r] + sWv[nf]) * wvv[nf];
    }
    // reduce across the 16 lanes sharing a row-group (cols)
#pragma unroll
    for (int m = 1; m < 16; m <<= 1)
#pragma unroll
        for (int mf = 0; mf < 4; ++mf)
#pragma unroll
            for (int r = 0; r < 4; ++r)
                pa[mf][r] += __shfl_xor(pa[mf][r], m, 64);

    if (l15 == 0) {
#pragma unroll
        for (int mf = 0; mf < 4; ++mf)
#pragma unroll
            for (int r = 0; r < 4; ++r)
                lred[wave][mf * 16 + lkg * 4 + r] = pa[mf][r];
    }
    __syncthreads();
    if (t < 64)
        atten[m0 + t] = lred[0][t] + lred[1][t] + lred[2][t] + lred[3][t];
}

// ---------------- softmax over S=2048 per batch row ----------------
__global__ __launch_bounds__(256) void softmax_kernel(const float* __restrict__ atten,
                                                      float* __restrict__ out) {
    int b = blockIdx.x, t = threadIdx.x;
    const float* row = atten + b * 2048;
    float v[8];
#pragma unroll
    for (int i = 0; i < 8; ++i) v[i] = row[t + 256 * i];
    float mx = v[0];
#pragma unroll
    for (int i = 1; i < 8; ++i) mx = fmaxf(mx, v[i]);
#pragma unroll
    for (int m = 1; m < 64; m <<= 1) mx = fmaxf(mx, __shfl_xor(mx, m, 64));
    __shared__ float redm[4], reds[4];
    if ((t & 63) == 0) redm[t >> 6] = mx;
    __syncthreads();
    mx = fmaxf(fmaxf(redm[0], redm[1]), fmaxf(redm[2], redm[3]));
    float sum = 0.f;
#pragma unroll
    for (int i = 0; i < 8; ++i) { v[i] = __expf(v[i] - mx); sum += v[i]; }
#pragma unroll
    for (int m = 1; m < 64; m <<= 1) sum += __shfl_xor(sum, m, 64);
    if ((t & 63) == 0) reds[t >> 6] = sum;
    __syncthreads();
    sum = reds[0] + reds[1] + reds[2] + reds[3];
    float inv = 1.0f / sum;
    float* soft = out + 32768;
#pragma unroll
    for (int i = 0; i < 8; ++i) soft[b * 2048 + t + 256 * i] = v[i] * inv;
}

// ---------------- context partial: 32 chunks of 64 rows per batch ----------
__global__ __launch_bounds__(256) void ctx_partial(const float* __restrict__ enc,
                                                   const float* __restrict__ soft,
                                                   float* __restrict__ part) {
    int blk = blockIdx.x;               // b*32 + chunk
    int b = blk >> 5, s0 = (blk & 31) * 64;
    int t = threadIdx.x;
    float4 a = {0.f, 0.f, 0.f, 0.f};
    const float* base = enc + ((size_t)(b * 2048 + s0)) * 1024 + t * 4;
    const float* sw = soft + b * 2048 + s0;
#pragma unroll 4
    for (int s = 0; s < 64; ++s) {
        float w = sw[s];
        float4 e = *(const float4*)(base + (size_t)s * 1024);
        a.x += w * e.x; a.y += w * e.y; a.z += w * e.z; a.w += w * e.w;
    }
    *(float4*)(part + (size_t)blk * 1024 + t * 4) = a;
}

__global__ __launch_bounds__(256) void ctx_reduce(const float* __restrict__ part,
                                                  float* __restrict__ ctx) {
    int id = blockIdx.x * 256 + threadIdx.x;  // 32768 = 32b * 1024e
    int b = id >> 10, e = id & 1023;
    float s = 0.f;
#pragma unroll 8
    for (int c = 0; c < 32; ++c) s += part[((size_t)(b * 32 + c)) * 1024 + e];
    ctx[id] = s;
}

extern "C" void kernel_launch(void* const* d_in, const int* in_sizes, int n_in,
                              void* d_out, int out_size, void* d_ws, size_t ws_size,
                              hipStream_t stream) {
    const float* s   = (const float*)d_in[0];
    const float* enc = (const float*)d_in[1];
    const float* Wat = (const float*)d_in[2];
    const float* Wv  = (const float*)d_in[3];
    float* out = (float*)d_out;

    char* ws = (char*)d_ws;
    float* sW            = (float*)ws;                                   // 64 KiB
    unsigned short* Webf = (unsigned short*)(ws + (64 << 10));           // 1 MiB
    float* atten         = (float*)(ws + (64 << 10) + (1 << 20));        // 256 KiB
    float* part          = (float*)(ws + (64 << 10) + (1 << 20) + (256 << 10)); // 4 MiB

    prep_sw<<<64, 256, 0, stream>>>(s, Wat, sW);
    prep_we<<<512, 256, 0, stream>>>(Wat, Webf);
    energy_kernel<<<1024, 256, 0, stream>>>(enc, Webf, sW, Wv, atten);
    softmax_kernel<<<32, 256, 0, stream>>>(atten, out);
    ctx_partial<<<1024, 256, 0, stream>>>(enc, out + 32768, part);
    ctx_reduce<<<128, 256, 0, stream>>>(part, out);
}

// Round 2
// 237.918 us; speedup vs baseline: 1.3920x; 1.3920x over previous
//
#include <hip/hip_runtime.h>
#include <hip/hip_bf16.h>

// Attention head: context/softmax over (B=32, S=2048, DEC=512, ENC2=1024)
// d_in[0] = s        (1,32,512)   f32
// d_in[1] = enc      (32,2048,1024) f32
// d_in[2] = W_attn   (512,1536)   f32   [:, :512]=W_s  [:,512:]=W_e
// d_in[3] = W_v      (1,512)      f32
// d_out   = context (32,1024) f32  ++  soft (32,2048) f32

typedef __attribute__((ext_vector_type(8))) short bf16x8;
typedef __attribute__((ext_vector_type(4))) float f32x4;

static __device__ __forceinline__ unsigned short f2bf(float f) {
    union { float f; unsigned u; } v; v.f = f;
    unsigned r = (v.u + 0x7fffu + ((v.u >> 16) & 1u)) >> 16;  // RNE
    return (unsigned short)r;
}

static __device__ __forceinline__ float fast_tanh(float x) {
    return 1.0f - 2.0f / (__expf(2.0f * x) + 1.0f);
}

// ---------------- prep: sW[b,h] = sum_d s[b,d] * W_attn[h, d] ----------------
__global__ __launch_bounds__(256) void prep_sw(const float* __restrict__ s,
                                               const float* __restrict__ Wat,
                                               float* __restrict__ sW) {
    int id = blockIdx.x * 256 + threadIdx.x;   // 16384 = 32b * 512h
    int b = id >> 9, h = id & 511;
    const float4* wr = (const float4*)(Wat + (size_t)h * 1536);
    const float4* sr = (const float4*)(s + (size_t)b * 512);
    float acc = 0.f;
#pragma unroll 8
    for (int i = 0; i < 128; ++i) {
        float4 w = wr[i], sv = sr[i];
        acc += w.x * sv.x + w.y * sv.y + w.z * sv.z + w.w * sv.w;
    }
    sW[id] = acc;
}

// ---------------- prep: Webf[h][e] = bf16(W_attn[h, 512+e]) ----------------
__global__ __launch_bounds__(256) void prep_we(const float* __restrict__ Wat,
                                               unsigned short* __restrict__ Webf) {
    int id = blockIdx.x * 256 + threadIdx.x;   // 131072 threads, 4 elems each
    int flat = id * 4;
    int h = flat >> 10, e = flat & 1023;
    float4 w = *(const float4*)(Wat + (size_t)h * 1536 + 512 + e);
    union { unsigned short us[4]; uint2 v; } p;
    p.us[0] = f2bf(w.x); p.us[1] = f2bf(w.y); p.us[2] = f2bf(w.z); p.us[3] = f2bf(w.w);
    *(uint2*)(Webf + flat) = p.v;
}

// ---------------- energy+atten: atten[m] = sum_h tanh(sW+enc.W_e^T)*Wv[h] ----
// Block: 64 rows (M) x 512 cols (N), 8 waves each own 64 cols.
// K-loop 1024 in steps of 64 (2 sub-steps of 32), double-buffered LDS,
// ONE barrier per K-step, next step's loads issued right after the barrier.
__global__ __launch_bounds__(512) void energy_kernel(
    const float* __restrict__ enc, const unsigned short* __restrict__ Webf,
    const float* __restrict__ sW, const float* __restrict__ Wv,
    float* __restrict__ atten) {
    __shared__ __align__(16) unsigned short lA[2][4096];  // [buf][kk*2048 + u*8]
    __shared__ float lred[8][64];

    const int t = threadIdx.x;       // 0..511
    const int lane = t & 63;
    const int wave = t >> 6;
    const int m0 = blockIdx.x * 64;
    const int b = m0 >> 11;
    const int l15 = lane & 15;
    const int lkg = lane >> 4;       // k-group 0..3
    const int n0 = wave * 64;

    float sWv[4], wvv[4];
#pragma unroll
    for (int nf = 0; nf < 4; ++nf) {
        int col = n0 + nf * 16 + l15;
        sWv[nf] = sW[(b << 9) + col];
        wvv[nf] = Wv[col];
    }

    f32x4 acc[4][4];
#pragma unroll
    for (int mf = 0; mf < 4; ++mf)
#pragma unroll
        for (int nf = 0; nf < 4; ++nf) acc[mf][nf] = (f32x4){0.f, 0.f, 0.f, 0.f};

    // staging role: thread t stages the 8 bf16 that fragment
    // (kk=t>>8, mf=(t&255)>>6, lane=t&63) will read -> conflict-free b128.
    const int u = t & 255;
    const int skk = t >> 8;                    // 0..1 k-substep
    const int srow = ((u >> 6) << 4) | (u & 15);
    const int skg = (u & 63) >> 4;
    const float* gA = enc + (size_t)(m0 + srow) * 1024 + skk * 32 + skg * 8;
    unsigned short* lst[2] = { &lA[0][skk * 2048 + u * 8], &lA[1][skk * 2048 + u * 8] };

    // prologue: load K-step 0
    float4 f0 = *(const float4*)(gA);
    float4 f1 = *(const float4*)(gA + 4);

    for (int i = 0; i < 16; ++i) {
        const int k0 = i * 64;
        union { unsigned short us[8]; int4 v; } pk;
        pk.us[0] = f2bf(f0.x); pk.us[1] = f2bf(f0.y);
        pk.us[2] = f2bf(f0.z); pk.us[3] = f2bf(f0.w);
        pk.us[4] = f2bf(f1.x); pk.us[5] = f2bf(f1.y);
        pk.us[6] = f2bf(f1.z); pk.us[7] = f2bf(f1.w);
        *(int4*)lst[i & 1] = pk.v;
        __syncthreads();                       // staging visible (single barrier)
        if (i < 15) {                          // issue next loads AFTER barrier:
            f0 = *(const float4*)(gA + (i + 1) * 64);      // they fly under the
            f1 = *(const float4*)(gA + (i + 1) * 64 + 4);  // MFMA compute below
        }
        const unsigned short* lbuf = lA[i & 1];
#pragma unroll
        for (int kk = 0; kk < 2; ++kk) {
            bf16x8 afr[4];
#pragma unroll
            for (int mf = 0; mf < 4; ++mf)
                afr[mf] = *(const bf16x8*)&lbuf[kk * 2048 + (mf * 64 + lane) * 8];
            const unsigned short* gB = Webf + k0 + kk * 32 + lkg * 8;
#pragma unroll
            for (int nf = 0; nf < 4; ++nf) {
                int col = n0 + nf * 16 + l15;
                bf16x8 bfr = *(const bf16x8*)(gB + (size_t)col * 1024);
#pragma unroll
                for (int mf = 0; mf < 4; ++mf)
                    acc[mf][nf] = __builtin_amdgcn_mfma_f32_16x16x32_bf16(
                        afr[mf], bfr, acc[mf][nf], 0, 0, 0);
            }
        }
    }

    // epilogue: tanh + dot with Wv over this wave's 64 cols
    float pa[4][4];
#pragma unroll
    for (int mf = 0; mf < 4; ++mf) {
#pragma unroll
        for (int r = 0; r < 4; ++r) pa[mf][r] = 0.f;
#pragma unroll
        for (int nf = 0; nf < 4; ++nf)
#pragma unroll
            for (int r = 0; r < 4; ++r)
                pa[mf][r] += fast_tanh(acc[mf][nf][r] + sWv[nf]) * wvv[nf];
    }
#pragma unroll
    for (int m = 1; m < 16; m <<= 1)
#pragma unroll
        for (int mf = 0; mf < 4; ++mf)
#pragma unroll
            for (int r = 0; r < 4; ++r)
                pa[mf][r] += __shfl_xor(pa[mf][r], m, 64);

    if (l15 == 0) {
#pragma unroll
        for (int mf = 0; mf < 4; ++mf)
#pragma unroll
            for (int r = 0; r < 4; ++r)
                lred[wave][mf * 16 + lkg * 4 + r] = pa[mf][r];
    }
    __syncthreads();
    if (t < 64) {
        float ssum = 0.f;
#pragma unroll
        for (int w = 0; w < 8; ++w) ssum += lred[w][t];
        atten[m0 + t] = ssum;
    }
}

// ---------------- softmax over S=2048 per batch row ----------------
__global__ __launch_bounds__(256) void softmax_kernel(const float* __restrict__ atten,
                                                      float* __restrict__ out) {
    int b = blockIdx.x, t = threadIdx.x;
    const float* row = atten + b * 2048;
    float v[8];
#pragma unroll
    for (int i = 0; i < 8; ++i) v[i] = row[t + 256 * i];
    float mx = v[0];
#pragma unroll
    for (int i = 1; i < 8; ++i) mx = fmaxf(mx, v[i]);
#pragma unroll
    for (int m = 1; m < 64; m <<= 1) mx = fmaxf(mx, __shfl_xor(mx, m, 64));
    __shared__ float redm[4], reds[4];
    if ((t & 63) == 0) redm[t >> 6] = mx;
    __syncthreads();
    mx = fmaxf(fmaxf(redm[0], redm[1]), fmaxf(redm[2], redm[3]));
    float sum = 0.f;
#pragma unroll
    for (int i = 0; i < 8; ++i) { v[i] = __expf(v[i] - mx); sum += v[i]; }
#pragma unroll
    for (int m = 1; m < 64; m <<= 1) sum += __shfl_xor(sum, m, 64);
    if ((t & 63) == 0) reds[t >> 6] = sum;
    __syncthreads();
    sum = reds[0] + reds[1] + reds[2] + reds[3];
    float inv = 1.0f / sum;
    float* soft = out + 32768;
#pragma unroll
    for (int i = 0; i < 8; ++i) soft[b * 2048 + t + 256 * i] = v[i] * inv;
}

// ---------------- context partial: 32 chunks of 64 rows per batch ----------
__global__ __launch_bounds__(256) void ctx_partial(const float* __restrict__ enc,
                                                   const float* __restrict__ soft,
                                                   float* __restrict__ part) {
    int blk = blockIdx.x;               // b*32 + chunk
    int b = blk >> 5, s0 = (blk & 31) * 64;
    int t = threadIdx.x;
    float4 a = {0.f, 0.f, 0.f, 0.f};
    const float* base = enc + ((size_t)(b * 2048 + s0)) * 1024 + t * 4;
    const float* sw = soft + b * 2048 + s0;
#pragma unroll 4
    for (int s = 0; s < 64; ++s) {
        float w = sw[s];
        float4 e = *(const float4*)(base + (size_t)s * 1024);
        a.x += w * e.x; a.y += w * e.y; a.z += w * e.z; a.w += w * e.w;
    }
    *(float4*)(part + (size_t)blk * 1024 + t * 4) = a;
}

__global__ __launch_bounds__(256) void ctx_reduce(const float* __restrict__ part,
                                                  float* __restrict__ ctx) {
    int id = blockIdx.x * 256 + threadIdx.x;  // 32768 = 32b * 1024e
    int b = id >> 10, e = id & 1023;
    float s = 0.f;
#pragma unroll 8
    for (int c = 0; c < 32; ++c) s += part[((size_t)(b * 32 + c)) * 1024 + e];
    ctx[id] = s;
}

extern "C" void kernel_launch(void* const* d_in, const int* in_sizes, int n_in,
                              void* d_out, int out_size, void* d_ws, size_t ws_size,
                              hipStream_t stream) {
    const float* s   = (const float*)d_in[0];
    const float* enc = (const float*)d_in[1];
    const float* Wat = (const float*)d_in[2];
    const float* Wv  = (const float*)d_in[3];
    float* out = (float*)d_out;

    char* ws = (char*)d_ws;
    float* sW            = (float*)ws;                                   // 64 KiB
    unsigned short* Webf = (unsigned short*)(ws + (64 << 10));           // 1 MiB
    float* atten         = (float*)(ws + (64 << 10) + (1 << 20));        // 256 KiB
    float* part          = (float*)(ws + (64 << 10) + (1 << 20) + (256 << 10)); // 4 MiB

    prep_sw<<<64, 256, 0, stream>>>(s, Wat, sW);
    prep_we<<<512, 256, 0, stream>>>(Wat, Webf);
    energy_kernel<<<1024, 512, 0, stream>>>(enc, Webf, sW, Wv, atten);
    softmax_kernel<<<32, 256, 0, stream>>>(atten, out);
    ctx_partial<<<1024, 256, 0, stream>>>(enc, out + 32768, part);
    ctx_reduce<<<128, 256, 0, stream>>>(part, out);
}

// Round 3
// 182.646 us; speedup vs baseline: 1.8133x; 1.3026x over previous
//
#include <hip/hip_runtime.h>
#include <hip/hip_bf16.h>

// Attention head: context/softmax over (B=32, S=2048, DEC=512, ENC2=1024)
// d_in[0] = s        (1,32,512)   f32
// d_in[1] = enc      (32,2048,1024) f32
// d_in[2] = W_attn   (512,1536)   f32   [:, :512]=W_s  [:,512:]=W_e
// d_in[3] = W_v      (1,512)      f32
// d_out   = context (32,1024) f32  ++  soft (32,2048) f32

typedef __attribute__((ext_vector_type(8))) short bf16x8;
typedef __attribute__((ext_vector_type(4))) float f32x4;
typedef __attribute__((address_space(3))) unsigned lds_u32;
typedef const __attribute__((address_space(1))) unsigned g_u32;

static __device__ __forceinline__ unsigned short f2bf(float f) {
    union { float f; unsigned u; } v; v.f = f;
    unsigned r = (v.u + 0x7fffu + ((v.u >> 16) & 1u)) >> 16;  // RNE
    return (unsigned short)r;
}

static __device__ __forceinline__ unsigned pk2(float x, float y) {
    union { __hip_bfloat162 h; unsigned u; } c;
    c.h = __float22bfloat162_rn(make_float2(x, y));  // compiles to v_cvt_pk_bf16_f32
    return c.u;
}

static __device__ __forceinline__ float fast_tanh(float x) {
    return 1.0f - 2.0f / (__expf(2.0f * x) + 1.0f);
}

// ---------------- prep: sW[b,h] = sum_d s[b,d] * W_attn[h, d] ----------------
__global__ __launch_bounds__(256) void prep_sw(const float* __restrict__ s,
                                               const float* __restrict__ Wat,
                                               float* __restrict__ sW) {
    int id = blockIdx.x * 256 + threadIdx.x;   // 16384 = 32b * 512h
    int b = id >> 9, h = id & 511;
    const float4* wr = (const float4*)(Wat + (size_t)h * 1536);
    const float4* sr = (const float4*)(s + (size_t)b * 512);
    float acc = 0.f;
#pragma unroll 8
    for (int i = 0; i < 128; ++i) {
        float4 w = wr[i], sv = sr[i];
        acc += w.x * sv.x + w.y * sv.y + w.z * sv.z + w.w * sv.w;
    }
    sW[id] = acc;
}

// ------- prep: WebfB fragment-major bf16 repack of W_e = W_attn[:,512:] -----
// Layout: [wave(8)][step(16)][kk(2)][nf(4)][lane(64)][j(8)]
// element = W_e[col = w*64+nf*16+(lane&15)][k = step*64+kk*32+(lane>>4)*8+j]
__global__ __launch_bounds__(256) void prep_weB(const float* __restrict__ Wat,
                                                unsigned short* __restrict__ WebfB) {
    int tid = blockIdx.x * 256 + threadIdx.x;  // 0..65535
    int lane = tid & 63;
    int g = tid >> 6;
    int nf = g & 3, kk = (g >> 2) & 1, i = (g >> 3) & 15, w = g >> 7;
    int col = w * 64 + nf * 16 + (lane & 15);
    int k0 = i * 64 + kk * 32 + (lane >> 4) * 8;
    const float* src = Wat + (size_t)col * 1536 + 512 + k0;
    float4 w0 = *(const float4*)src;
    float4 w1 = *(const float4*)(src + 4);
    union { unsigned short us[8]; int4 v; } p;
    p.us[0] = f2bf(w0.x); p.us[1] = f2bf(w0.y); p.us[2] = f2bf(w0.z); p.us[3] = f2bf(w0.w);
    p.us[4] = f2bf(w1.x); p.us[5] = f2bf(w1.y); p.us[6] = f2bf(w1.z); p.us[7] = f2bf(w1.w);
    *(int4*)(WebfB + (size_t)tid * 8) = p.v;
}

// ---------------- energy+atten: atten[m] = sum_h tanh(sW+enc.W_e^T)*Wv[h] ----
// Block: 64 rows x 512 cols, 8 waves x 64 cols. K-step 64, dbuf LDS.
// A: global_load_lds (coalesced, XOR-swizzled source), f32 in LDS,
//    cvt->bf16 on fragment read. B: fragment-major contiguous loads.
// Issue order per step: B loads (L2) | A prefetch (HBM) | compute.
__global__ __launch_bounds__(512) void energy_kernel(
    const float* __restrict__ enc, const unsigned short* __restrict__ WebfB,
    const float* __restrict__ sW, const float* __restrict__ Wv,
    float* __restrict__ atten) {
    __shared__ __align__(16) float lA[2][4096];  // [buf][row*64 + swz_chunk*4], 32 KiB
    __shared__ float lred[8][64];

    const int t = threadIdx.x;       // 0..511
    const int lane = t & 63;
    const int wave = t >> 6;
    const int m0 = blockIdx.x * 64;
    const int b = m0 >> 11;
    const int l15 = lane & 15;
    const int lkg = lane >> 4;       // k-group 0..3
    const int n0 = wave * 64;

    // A gload source pointers (q=0,1): row rq, inverse-swizzled chunk
    const int r0 = wave * 8 + (lane >> 4);          // (wave*2+0)*4 + l>>4
    const int r1 = r0 + 4;
    const int cl0 = l15 ^ (r0 & 7);
    const int cl1 = l15 ^ (r1 & 7);
    const float* g0 = enc + (size_t)(m0 + r0) * 1024 + cl0 * 4;
    const float* g1 = enc + (size_t)(m0 + r1) * 1024 + cl1 * 4;
    // wave-uniform LDS dest bases (floats)
    const int ld0 = (wave * 2 + 0) * 256;
    const int ld1 = (wave * 2 + 1) * 256;

    const unsigned short* wB = WebfB + (size_t)wave * 65536 + lane * 8;

    f32x4 acc[4][4];
#pragma unroll
    for (int mf = 0; mf < 4; ++mf)
#pragma unroll
        for (int nf = 0; nf < 4; ++nf) acc[mf][nf] = (f32x4){0.f, 0.f, 0.f, 0.f};

    // prologue: stage step 0 into buf 0
    __builtin_amdgcn_global_load_lds((g_u32*)g0, (lds_u32*)&lA[0][ld0], 16, 0, 0);
    __builtin_amdgcn_global_load_lds((g_u32*)g1, (lds_u32*)&lA[0][ld1], 16, 0, 0);
    __syncthreads();

    for (int i = 0; i < 16; ++i) {
        const int cur = i & 1;
        // --- B fragment loads first (L2-resident, contiguous 16B/lane) ---
        bf16x8 bfr[2][4];
#pragma unroll
        for (int kk = 0; kk < 2; ++kk)
#pragma unroll
            for (int nf = 0; nf < 4; ++nf)
                bfr[kk][nf] = *(const bf16x8*)(wB + (((i * 2 + kk) * 4 + nf) << 9));
        __builtin_amdgcn_sched_barrier(0);
        // --- A prefetch for next step (HBM), issued after B so B-waits
        //     never transitively wait on HBM ---
        if (i < 15) {
            __builtin_amdgcn_global_load_lds((g_u32*)(g0 + (i + 1) * 64),
                                             (lds_u32*)&lA[cur ^ 1][ld0], 16, 0, 0);
            __builtin_amdgcn_global_load_lds((g_u32*)(g1 + (i + 1) * 64),
                                             (lds_u32*)&lA[cur ^ 1][ld1], 16, 0, 0);
        }
        __builtin_amdgcn_sched_barrier(0);
        // --- compute from lA[cur]: swizzled ds_read_b128 + cvt + MFMA ---
        const float* lbuf = lA[cur];
#pragma unroll
        for (int kk = 0; kk < 2; ++kk) {
            const int c0 = kk * 8 + lkg * 2;
#pragma unroll
            for (int mf = 0; mf < 4; ++mf) {
                const int r = mf * 16 + l15;
                const int r7 = r & 7;
                float4 a0 = *(const float4*)&lbuf[r * 64 + ((c0 ^ r7) << 2)];
                float4 a1 = *(const float4*)&lbuf[r * 64 + (((c0 + 1) ^ r7) << 2)];
                union { unsigned u[4]; bf16x8 v; } af;
                af.u[0] = pk2(a0.x, a0.y); af.u[1] = pk2(a0.z, a0.w);
                af.u[2] = pk2(a1.x, a1.y); af.u[3] = pk2(a1.z, a1.w);
#pragma unroll
                for (int nf = 0; nf < 4; ++nf)
                    acc[mf][nf] = __builtin_amdgcn_mfma_f32_16x16x32_bf16(
                        af.v, bfr[kk][nf], acc[mf][nf], 0, 0, 0);
            }
        }
        __syncthreads();
    }

    // epilogue: tanh + dot with Wv over this wave's 64 cols
    float sWv[4], wvv[4];
#pragma unroll
    for (int nf = 0; nf < 4; ++nf) {
        int col = n0 + nf * 16 + l15;
        sWv[nf] = sW[(b << 9) + col];
        wvv[nf] = Wv[col];
    }
    float pa[4][4];
#pragma unroll
    for (int mf = 0; mf < 4; ++mf) {
#pragma unroll
        for (int r = 0; r < 4; ++r) pa[mf][r] = 0.f;
#pragma unroll
        for (int nf = 0; nf < 4; ++nf)
#pragma unroll
            for (int r = 0; r < 4; ++r)
                pa[mf][r] += fast_tanh(acc[mf][nf][r] + sWv[nf]) * wvv[nf];
    }
#pragma unroll
    for (int m = 1; m < 16; m <<= 1)
#pragma unroll
        for (int mf = 0; mf < 4; ++mf)
#pragma unroll
            for (int r = 0; r < 4; ++r)
                pa[mf][r] += __shfl_xor(pa[mf][r], m, 64);

    if (l15 == 0) {
#pragma unroll
        for (int mf = 0; mf < 4; ++mf)
#pragma unroll
            for (int r = 0; r < 4; ++r)
                lred[wave][mf * 16 + lkg * 4 + r] = pa[mf][r];
    }
    __syncthreads();
    if (t < 64) {
        float ssum = 0.f;
#pragma unroll
        for (int w = 0; w < 8; ++w) ssum += lred[w][t];
        atten[m0 + t] = ssum;
    }
}

// ---------------- softmax over S=2048 per batch row ----------------
__global__ __launch_bounds__(256) void softmax_kernel(const float* __restrict__ atten,
                                                      float* __restrict__ out) {
    int b = blockIdx.x, t = threadIdx.x;
    const float* row = atten + b * 2048;
    float v[8];
#pragma unroll
    for (int i = 0; i < 8; ++i) v[i] = row[t + 256 * i];
    float mx = v[0];
#pragma unroll
    for (int i = 1; i < 8; ++i) mx = fmaxf(mx, v[i]);
#pragma unroll
    for (int m = 1; m < 64; m <<= 1) mx = fmaxf(mx, __shfl_xor(mx, m, 64));
    __shared__ float redm[4], reds[4];
    if ((t & 63) == 0) redm[t >> 6] = mx;
    __syncthreads();
    mx = fmaxf(fmaxf(redm[0], redm[1]), fmaxf(redm[2], redm[3]));
    float sum = 0.f;
#pragma unroll
    for (int i = 0; i < 8; ++i) { v[i] = __expf(v[i] - mx); sum += v[i]; }
#pragma unroll
    for (int m = 1; m < 64; m <<= 1) sum += __shfl_xor(sum, m, 64);
    if ((t & 63) == 0) reds[t >> 6] = sum;
    __syncthreads();
    sum = reds[0] + reds[1] + reds[2] + reds[3];
    float inv = 1.0f / sum;
    float* soft = out + 32768;
#pragma unroll
    for (int i = 0; i < 8; ++i) soft[b * 2048 + t + 256 * i] = v[i] * inv;
}

// ---------------- context partial: 32 chunks of 64 rows per batch ----------
__global__ __launch_bounds__(256) void ctx_partial(const float* __restrict__ enc,
                                                   const float* __restrict__ soft,
                                                   float* __restrict__ part) {
    int blk = blockIdx.x;               // b*32 + chunk
    int b = blk >> 5, s0 = (blk & 31) * 64;
    int t = threadIdx.x;
    float4 a = {0.f, 0.f, 0.f, 0.f};
    const float* base = enc + ((size_t)(b * 2048 + s0)) * 1024 + t * 4;
    const float* sw = soft + b * 2048 + s0;
#pragma unroll 4
    for (int s = 0; s < 64; ++s) {
        float w = sw[s];
        float4 e = *(const float4*)(base + (size_t)s * 1024);
        a.x += w * e.x; a.y += w * e.y; a.z += w * e.z; a.w += w * e.w;
    }
    *(float4*)(part + (size_t)blk * 1024 + t * 4) = a;
}

__global__ __launch_bounds__(256) void ctx_reduce(const float* __restrict__ part,
                                                  float* __restrict__ ctx) {
    int id = blockIdx.x * 256 + threadIdx.x;  // 32768 = 32b * 1024e
    int b = id >> 10, e = id & 1023;
    float s = 0.f;
#pragma unroll 8
    for (int c = 0; c < 32; ++c) s += part[((size_t)(b * 32 + c)) * 1024 + e];
    ctx[id] = s;
}

extern "C" void kernel_launch(void* const* d_in, const int* in_sizes, int n_in,
                              void* d_out, int out_size, void* d_ws, size_t ws_size,
                              hipStream_t stream) {
    const float* s   = (const float*)d_in[0];
    const float* enc = (const float*)d_in[1];
    const float* Wat = (const float*)d_in[2];
    const float* Wv  = (const float*)d_in[3];
    float* out = (float*)d_out;

    char* ws = (char*)d_ws;
    float* sW             = (float*)ws;                                   // 64 KiB
    unsigned short* WebfB = (unsigned short*)(ws + (64 << 10));           // 1 MiB
    float* atten          = (float*)(ws + (64 << 10) + (1 << 20));        // 256 KiB
    float* part           = (float*)(ws + (64 << 10) + (1 << 20) + (256 << 10)); // 4 MiB

    prep_sw<<<64, 256, 0, stream>>>(s, Wat, sW);
    prep_weB<<<256, 256, 0, stream>>>(Wat, WebfB);
    energy_kernel<<<1024, 512, 0, stream>>>(enc, WebfB, sW, Wv, atten);
    softmax_kernel<<<32, 256, 0, stream>>>(atten, out);
    ctx_partial<<<1024, 256, 0, stream>>>(enc, out + 32768, part);
    ctx_reduce<<<128, 256, 0, stream>>>(part, out);
}